// Round 6
// baseline (460.630 us; speedup 1.0000x reference)
//
#include <hip/hip_runtime.h>
#include <cstdint>
#include <cstddef>

// Problem constants
#define NTOK 2048      // B*S
#define DDIM 1024
#define FDIM 2048
#define NEXP 14
#define MAXT 2048
#define BM   160       // m-tile rows: ceil(~293/160)=2 m-tiles/expert

typedef __attribute__((ext_vector_type(8))) short short8;
typedef __attribute__((ext_vector_type(4))) float floatx4;

__device__ __forceinline__ unsigned pack2bf(float lo, float hi) {
    unsigned a = __float_as_uint(lo), b = __float_as_uint(hi);
    return ((a + 0x8000u) >> 16) | ((b + 0x8000u) & 0xffff0000u);
}
__device__ __forceinline__ unsigned short f2bf1(float f) {
    return (unsigned short)((__float_as_uint(f) + 0x8000u) >> 16);
}

// async global->LDS, 16B per lane; lds base must be wave-uniform
__device__ __forceinline__ void glds16(const void* g, void* lds) {
    __builtin_amdgcn_global_load_lds((const __attribute__((address_space(1))) unsigned*)g,
                                     (__attribute__((address_space(3))) unsigned*)lds, 16, 0, 0);
}

// (fallback path only) B LDS chunk swizzle
__device__ __forceinline__ int bswz(int n) { return ((n >> 2) ^ n ^ (n >> 4)) & 7; }

#define SBAR() __builtin_amdgcn_sched_barrier(0)

// ---------------- convert x -> bf16, zero counters ----------------
__global__ __launch_bounds__(256) void cvtx_kernel(const float* __restrict__ x,
                                                   unsigned short* __restrict__ xb,
                                                   int* __restrict__ cnt) {
    if (blockIdx.x == 0 && threadIdx.x < NEXP) cnt[threadIdx.x] = 0;
    const size_t i = ((size_t)blockIdx.x * 256 + threadIdx.x) * 8;
    float4 a = *(const float4*)(x + i);
    float4 b = *(const float4*)(x + i + 4);
    uint4 u;
    u.x = pack2bf(a.x, a.y); u.y = pack2bf(a.z, a.w);
    u.z = pack2bf(b.x, b.y); u.w = pack2bf(b.z, b.w);
    *(uint4*)(xb + i) = u;
}

// ---------------- gating: one wave per token ----------------
__global__ __launch_bounds__(256) void gate_kernel(
    const float* __restrict__ x, const float* __restrict__ gw,
    int* __restrict__ cnt, int* __restrict__ lists, float* __restrict__ wt)
{
    const int wave = threadIdx.x >> 6, lane = threadIdx.x & 63;
    const int n = blockIdx.x * 4 + wave;
    float part[NEXP];
#pragma unroll
    for (int e = 0; e < NEXP; ++e) part[e] = 0.f;
    const float4* xr = (const float4*)(x + (size_t)n * DDIM);
#pragma unroll
    for (int kk = 0; kk < 4; ++kk) {
        const float4 xv = xr[kk * 64 + lane];
#pragma unroll
        for (int e = 0; e < NEXP; ++e) {
            const float4 g = ((const float4*)(gw + e * DDIM))[kk * 64 + lane];
            part[e] = fmaf(xv.x, g.x, fmaf(xv.y, g.y, fmaf(xv.z, g.z, fmaf(xv.w, g.w, part[e]))));
        }
    }
#pragma unroll
    for (int e = 0; e < NEXP; ++e) {
        float v = part[e];
        for (int off = 32; off; off >>= 1) v += __shfl_xor(v, off);
        part[e] = v;
    }
    int i0 = 0; float l0 = part[0];
#pragma unroll
    for (int e = 1; e < NEXP; ++e) if (part[e] > l0) { l0 = part[e]; i0 = e; }
    int i1 = -1; float l1 = -3.0e38f;
#pragma unroll
    for (int e = 0; e < NEXP; ++e) if (e != i0 && part[e] > l1) { l1 = part[e]; i1 = e; }
    if (lane == 0) {
        const float r  = __expf(l1 - l0);
        wt[2 * n]     = 1.f / (1.f + r);
        wt[2 * n + 1] = r / (1.f + r);
        int p0 = atomicAdd(&cnt[i0], 1); lists[i0 * MAXT + p0] = 2 * n;
        int p1 = atomicAdd(&cnt[i1], 1); lists[i1 * MAXT + p1] = 2 * n + 1;
    }
}

// ---------------- build compact (expert, m-tile) job list ----------------
#define MAXJOBS 40
__global__ void jobs_kernel(const int* __restrict__ cnt, int* __restrict__ job_e,
                            int* __restrict__ job_mt, int* __restrict__ njobs) {
    if (threadIdx.x == 0) {
        int J = 0;
        for (int e = 0; e < NEXP; ++e) {
            const int m = (cnt[e] + BM - 1) / BM;
            for (int i = 0; i < m; ++i) { job_e[J] = e; job_mt[J] = i; ++J; }
        }
        njobs[0] = J;
    }
}

// ============ weight retile+cast pre-passes (f32 strided -> bf16 panels) ============
// Reads are 100% LINEAR (contiguous 8-row slabs); LDS does the k-transpose;
// writes land in panel order: wb[(e,nt,kt)][c 0..7][n 0..127][j 0..7] bf16,
// which is byte-for-byte the order the GEMM's glds16 staging consumes.

// w1 [E][1024][2048] -> wb1 panels (e*16+nt)*16+kt, 16KB each
__global__ __launch_bounds__(256) void retile1_kernel(const float* __restrict__ w1,
                                                      unsigned short* __restrict__ wb1) {
    __shared__ unsigned short lb[8 * 2048];          // 32 KB
    const int bid = blockIdx.x;                      // 14*128
    const int e = bid >> 7, r8 = bid & 127;
    const int kt = r8 >> 3, c = r8 & 7;
    const int t = threadIdx.x;
    const float* src = w1 + ((size_t)e * 1024 + r8 * 8) * 2048;
#pragma unroll
    for (int jr = 0; jr < 8; ++jr) {
        float4 v0 = *(const float4*)(src + (size_t)jr * 2048 + t * 8);
        float4 v1 = *(const float4*)(src + (size_t)jr * 2048 + t * 8 + 4);
        uint4 u;
        u.x = pack2bf(v0.x, v0.y); u.y = pack2bf(v0.z, v0.w);
        u.z = pack2bf(v1.x, v1.y); u.w = pack2bf(v1.z, v1.w);
        *(uint4*)&lb[jr * 2048 + t * 8] = u;
    }
    __syncthreads();
#pragma unroll
    for (int o = 0; o < 8; ++o) {
        const int f = t + o * 256;
        const int nt = f >> 7, n = f & 127;
        uint4 u;
        u.x = lb[0 * 2048 + f] | ((unsigned)lb[1 * 2048 + f] << 16);
        u.y = lb[2 * 2048 + f] | ((unsigned)lb[3 * 2048 + f] << 16);
        u.z = lb[4 * 2048 + f] | ((unsigned)lb[5 * 2048 + f] << 16);
        u.w = lb[6 * 2048 + f] | ((unsigned)lb[7 * 2048 + f] << 16);
        *(uint4*)&wb1[(((size_t)(e * 16 + nt) * 16 + kt) * 8192) + (c * 128 + n) * 8] = u;
    }
}

// w2 [E][2048][1024] -> wb2 panels (e*8+nt)*32+kt, 16KB each
__global__ __launch_bounds__(256) void retile2_kernel(const float* __restrict__ w2,
                                                      unsigned short* __restrict__ wb2) {
    __shared__ unsigned short lb[8 * 1024];          // 16 KB
    const int bid = blockIdx.x;                      // 14*256
    const int e = bid >> 8, r8 = bid & 255;
    const int kt = r8 >> 3, c = r8 & 7;
    const int t = threadIdx.x;
    const float* src = w2 + ((size_t)e * 2048 + r8 * 8) * 1024;
#pragma unroll
    for (int jr = 0; jr < 8; ++jr) {
        float4 v0 = *(const float4*)(src + (size_t)jr * 1024 + t * 4);
        uint2 u;
        u.x = pack2bf(v0.x, v0.y); u.y = pack2bf(v0.z, v0.w);
        *(uint2*)&lb[jr * 1024 + t * 4] = u;
    }
    __syncthreads();
#pragma unroll
    for (int o = 0; o < 4; ++o) {
        const int f = t + o * 256;
        const int nt = f >> 7, n = f & 127;
        uint4 u;
        u.x = lb[0 * 1024 + f] | ((unsigned)lb[1 * 1024 + f] << 16);
        u.y = lb[2 * 1024 + f] | ((unsigned)lb[3 * 1024 + f] << 16);
        u.z = lb[4 * 1024 + f] | ((unsigned)lb[5 * 1024 + f] << 16);
        u.w = lb[6 * 1024 + f] | ((unsigned)lb[7 * 1024 + f] << 16);
        *(uint4*)&wb2[(((size_t)(e * 8 + nt) * 32 + kt) * 8192) + (c * 128 + n) * 8] = u;
    }
}

// ======== shared A-staging + compute macros ========
// A: wave stages rows wave*40..+39 (5 x 8-row glds16), source chunk pre-swizzled.
#define STAGEA(buf, koff) {                                                   \
    _Pragma("unroll") for (int q = 0; q < 5; ++q)                             \
        glds16(aGp[q] + (koff), &As[buf][(wave * 40 + q * 8) * 64]); }

// New-path B staging: 4 glds16/wave from linear panel block (step = kt index)
#define STAGEB(buf, step) {                                                   \
    _Pragma("unroll") for (int q = 0; q < 4; ++q)                             \
        glds16(bsrc[q] + (size_t)(step) * 8192, &Bs[buf][(wave * 4 + q) * 512]); }

// New-path compute: Bs layout [c][n] (shorts idx = c*1024 + n*8) -> conflict-free
#define COMPUTE_N(buf) {                                                      \
    _Pragma("unroll") for (int ks = 0; ks < 2; ++ks) {                        \
        const int c_ = ks * 4 + lq;                                           \
        short8 af[5], bf[4];                                                  \
        _Pragma("unroll") for (int ii = 0; ii < 5; ++ii) {                    \
            const int r_ = wm + ii * 16 + lrow;                               \
            af[ii] = *(const short8*)&As[buf][r_ * 64 + ((c_ ^ (r_ & 7)) * 8)]; } \
        _Pragma("unroll") for (int jn = 0; jn < 4; ++jn) {                    \
            const int n_ = wn + jn * 16 + lrow;                               \
            bf[jn] = *(const short8*)&Bs[buf][c_ * 1024 + n_ * 8]; }          \
        __builtin_amdgcn_s_setprio(1);                                        \
        _Pragma("unroll") for (int ii = 0; ii < 5; ++ii)                      \
            _Pragma("unroll") for (int jn = 0; jn < 4; ++jn)                  \
                acc[ii][jn] = __builtin_amdgcn_mfma_f32_16x16x32_bf16(af[ii], bf[jn], acc[ii][jn], 0, 0, 0); \
        __builtin_amdgcn_s_setprio(0); } }

// ---------------- GEMM1 (retiled): hh[p][F] = gelu(xb @ w1b + b1) ----------------
// BM=160, BN=128, BK=64, NK=16; all staging via glds16; 1 barrier/step.
__global__ __launch_bounds__(256, 2) void gemm1_kernel(
    const unsigned short* __restrict__ xb, const unsigned short* __restrict__ wb1,
    const float* __restrict__ b1, const int* __restrict__ cnt,
    const int* __restrict__ lists, const int* __restrict__ job_e,
    const int* __restrict__ job_mt, const int* __restrict__ njobs,
    unsigned short* __restrict__ hh)
{
    const int nt = blockIdx.x, j = blockIdx.y;
    if (j >= njobs[0]) return;
    const int e = job_e[j], mt = job_mt[j];
    const int count = cnt[e];
    const int* list = lists + e * MAXT + mt * BM;
    const int mloc = min(BM, count - mt * BM);

    __shared__ __align__(16) unsigned short As[2][BM * 64];    // 40 KB
    __shared__ __align__(16) unsigned short Bs[2][8192];       // 32 KB

    const int t = threadIdx.x, lane = t & 63, wave = t >> 6;
    const int lrow = lane & 15, lq = lane >> 4;
    const int wm = (wave & 1) * 80, wn = (wave >> 1) * 64;

    const int achk = (lane & 7) ^ (lane >> 3);
    const unsigned short* aGp[5];
#pragma unroll
    for (int q = 0; q < 5; ++q) {
        const int r = wave * 40 + q * 8 + (lane >> 3);
        aGp[q] = xb + (size_t)(list[min(r, mloc - 1)] >> 1) * DDIM + achk * 8;
    }
    const unsigned short* bP = wb1 + ((size_t)(e * 16 + nt) * 16) * 8192;
    const unsigned short* bsrc[4];
#pragma unroll
    for (int q = 0; q < 4; ++q) bsrc[q] = bP + (wave * 4 + q) * 512 + lane * 8;

    floatx4 acc[5][4];
#pragma unroll
    for (int ii = 0; ii < 5; ++ii)
#pragma unroll
        for (int jn = 0; jn < 4; ++jn) acc[ii][jn] = (floatx4)0.f;

    STAGEA(0, 0); STAGEB(0, 0);
    __syncthreads();
#pragma unroll 1
    for (int i = 0; i < 15; ++i) {
        const int buf = i & 1;
        STAGEA(buf ^ 1, (i + 1) * 64);
        STAGEB(buf ^ 1, i + 1);
        COMPUTE_N(buf);
        __syncthreads();
    }
    COMPUTE_N(1);

    // epilogue: bias + exact gelu -> hh (bf16)
#pragma unroll
    for (int jn = 0; jn < 4; ++jn) {
        const int n = nt * 128 + wn + jn * 16 + lrow;
        const float bias = b1[e * FDIM + n];
#pragma unroll
        for (int ii = 0; ii < 5; ++ii) {
#pragma unroll
            for (int r = 0; r < 4; ++r) {
                const int m = wm + ii * 16 + lq * 4 + r;
                if (m < mloc) {
                    const int pp = list[m];
                    float v = acc[ii][jn][r] + bias;
                    v = 0.5f * v * (1.0f + erff(v * 0.70710678118654752f));
                    hh[(size_t)pp * FDIM + n] = f2bf1(v);
                }
            }
        }
    }
}

// ---------------- GEMM2 (retiled): out_slot = wt * (hh @ w2b + b2) ----------------
// BM=160, BN=128, BK=64, NK=32; direct stores.
__global__ __launch_bounds__(256, 2) void gemm2_kernel(
    const unsigned short* __restrict__ hh, const unsigned short* __restrict__ wb2,
    const float* __restrict__ b2, const int* __restrict__ cnt,
    const int* __restrict__ lists, const int* __restrict__ job_e,
    const int* __restrict__ job_mt, const int* __restrict__ njobs,
    const float* __restrict__ wt, float* __restrict__ out0, float* __restrict__ out1)
{
    const int nt = blockIdx.x, j = blockIdx.y;
    if (j >= njobs[0]) return;
    const int e = job_e[j], mt = job_mt[j];
    const int count = cnt[e];
    const int* list = lists + e * MAXT + mt * BM;
    const int mloc = min(BM, count - mt * BM);

    __shared__ __align__(16) unsigned short As[2][BM * 64];    // 40 KB
    __shared__ __align__(16) unsigned short Bs[2][8192];       // 32 KB

    const int t = threadIdx.x, lane = t & 63, wave = t >> 6;
    const int lrow = lane & 15, lq = lane >> 4;
    const int wm = (wave & 1) * 80, wn = (wave >> 1) * 64;

    const int achk = (lane & 7) ^ (lane >> 3);
    const unsigned short* aGp[5];
#pragma unroll
    for (int q = 0; q < 5; ++q) {
        const int r = wave * 40 + q * 8 + (lane >> 3);
        aGp[q] = hh + (size_t)list[min(r, mloc - 1)] * FDIM + achk * 8;
    }
    const unsigned short* bP = wb2 + ((size_t)(e * 8 + nt) * 32) * 8192;
    const unsigned short* bsrc[4];
#pragma unroll
    for (int q = 0; q < 4; ++q) bsrc[q] = bP + (wave * 4 + q) * 512 + lane * 8;

    floatx4 acc[5][4];
#pragma unroll
    for (int ii = 0; ii < 5; ++ii)
#pragma unroll
        for (int jn = 0; jn < 4; ++jn) acc[ii][jn] = (floatx4)0.f;

    STAGEA(0, 0); STAGEB(0, 0);
    __syncthreads();
#pragma unroll 1
    for (int i = 0; i < 31; ++i) {
        const int buf = i & 1;
        STAGEA(buf ^ 1, (i + 1) * 64);
        STAGEB(buf ^ 1, i + 1);
        COMPUTE_N(buf);
        __syncthreads();
    }
    COMPUTE_N(1);

#pragma unroll
    for (int jn = 0; jn < 4; ++jn) {
        const int n = nt * 128 + wn + jn * 16 + lrow;
        const float bias = b2[e * DDIM + n];
#pragma unroll
        for (int ii = 0; ii < 5; ++ii) {
#pragma unroll
            for (int r = 0; r < 4; ++r) {
                const int m = wm + ii * 16 + lq * 4 + r;
                if (m < mloc) {
                    const int pp = list[m];
                    const int tok = pp >> 1;
                    const float v = (acc[ii][jn][r] + bias) * wt[pp];
                    float* dst = (pp & 1) ? out1 : out0;
                    dst[(size_t)tok * DDIM + n] = v;
                }
            }
        }
    }
}

// ======== FALLBACK path (round-5 kernels, used if ws too small) ========
#define LOADB(dst, kbase, STRIDE) {                                           \
    _Pragma("unroll") for (int jj = 0; jj < 8; ++jj)                          \
        dst[jj] = *(const floatx4*)(bG + (size_t)((kbase) + kg * 8 + jj) * (STRIDE)); }

#define WRITEB(src, buf) {                                                    \
    _Pragma("unroll") for (int nn = 0; nn < 4; ++nn) {                        \
        const int n_ = n4 + nn, slot_ = kg ^ bswz(n_);                        \
        uint4 u_;                                                             \
        u_.x = pack2bf(src[0][nn], src[1][nn]); u_.y = pack2bf(src[2][nn], src[3][nn]); \
        u_.z = pack2bf(src[4][nn], src[5][nn]); u_.w = pack2bf(src[6][nn], src[7][nn]); \
        *(uint4*)&Bs[buf][n_ * 64 + slot_ * 8] = u_; } }

#define COMPUTE_F(buf) {                                                      \
    _Pragma("unroll") for (int ks = 0; ks < 2; ++ks) {                        \
        const int c_ = ks * 4 + lq;                                           \
        short8 af[5], bf[4];                                                  \
        _Pragma("unroll") for (int ii = 0; ii < 5; ++ii) {                    \
            const int r_ = wm + ii * 16 + lrow;                               \
            af[ii] = *(const short8*)&As[buf][r_ * 64 + ((c_ ^ (r_ & 7)) * 8)]; } \
        _Pragma("unroll") for (int jn = 0; jn < 4; ++jn) {                    \
            const int n_ = wn + jn * 16 + lrow;                               \
            bf[jn] = *(const short8*)&Bs[buf][n_ * 64 + ((c_ ^ bswz(n_)) * 8)]; } \
        __builtin_amdgcn_s_setprio(1);                                        \
        _Pragma("unroll") for (int ii = 0; ii < 5; ++ii)                      \
            _Pragma("unroll") for (int jn = 0; jn < 4; ++jn)                  \
                acc[ii][jn] = __builtin_amdgcn_mfma_f32_16x16x32_bf16(af[ii], bf[jn], acc[ii][jn], 0, 0, 0); \
        __builtin_amdgcn_s_setprio(0); } }

#define STEADY(i, curbuf, brv_c, brv_n, STRIDE) {                             \
    STAGEA((curbuf) ^ 1, ((i) + 1) * 64);                                     \
    WRITEB(brv_c, (curbuf) ^ 1);                                              \
    SBAR();                                                                   \
    LOADB(brv_n, ((i) + 2) * 64, STRIDE);                                     \
    SBAR();                                                                   \
    COMPUTE_F(curbuf);                                                        \
    asm volatile("s_waitcnt vmcnt(8) lgkmcnt(0)" ::: "memory");               \
    __builtin_amdgcn_s_barrier(); }

__global__ __launch_bounds__(256, 2) void gemm1_fb(
    const unsigned short* __restrict__ xb, const float* __restrict__ w1,
    const float* __restrict__ b1, const int* __restrict__ cnt,
    const int* __restrict__ lists, const int* __restrict__ job_e,
    const int* __restrict__ job_mt, const int* __restrict__ njobs,
    unsigned short* __restrict__ hh)
{
    const int id = blockIdx.x;
    const int j  = (id >> 7) * 8 + (id & 7);
    const int nt = (id >> 3) & 15;
    if (j >= njobs[0]) return;
    const int e = job_e[j], mt = job_mt[j];
    const int count = cnt[e];
    const int* list = lists + e * MAXT + mt * BM;
    const int mloc = min(BM, count - mt * BM);

    __shared__ __align__(16) unsigned short As[2][BM * 64];
    __shared__ __align__(16) unsigned short Bs[2][128 * 64];

    const int t = threadIdx.x, lane = t & 63, wave = t >> 6;
    const int lrow = lane & 15, lq = lane >> 4;
    const int wm = (wave & 1) * 80, wn = (wave >> 1) * 64;

    const int achk = (lane & 7) ^ (lane >> 3);
    const unsigned short* aGp[5];
#pragma unroll
    for (int q = 0; q < 5; ++q) {
        const int r = wave * 40 + q * 8 + (lane >> 3);
        aGp[q] = xb + (size_t)(list[min(r, mloc - 1)] >> 1) * DDIM + achk * 8;
    }
    const int n4 = (t & 31) * 4, kg = t >> 5;
    const float* bG = w1 + (size_t)e * DDIM * FDIM + nt * 128 + n4;

    floatx4 acc[5][4];
#pragma unroll
    for (int ii = 0; ii < 5; ++ii)
#pragma unroll
        for (int jn = 0; jn < 4; ++jn) acc[ii][jn] = (floatx4)0.f;

    floatx4 brvA[8], brvB[8];
    STAGEA(0, 0);
    SBAR();
    LOADB(brvB, 0, FDIM);
    WRITEB(brvB, 0);
    SBAR();
    LOADB(brvA, 64, FDIM);
    asm volatile("s_waitcnt vmcnt(8) lgkmcnt(0)" ::: "memory");
    __builtin_amdgcn_s_barrier();
#pragma unroll 1
    for (int it = 0; it < 7; ++it) {
        const int i = it * 2;
        STEADY(i, 0, brvA, brvB, FDIM);
        STEADY(i + 1, 1, brvB, brvA, FDIM);
    }
    STAGEA(1, 15 * 64);
    WRITEB(brvA, 1);
    SBAR();
    COMPUTE_F(0);
    asm volatile("s_waitcnt vmcnt(0) lgkmcnt(0)" ::: "memory");
    __builtin_amdgcn_s_barrier();
    COMPUTE_F(1);

#pragma unroll
    for (int jn = 0; jn < 4; ++jn) {
        const int n = nt * 128 + wn + jn * 16 + lrow;
        const float bias = b1[e * FDIM + n];
#pragma unroll
        for (int ii = 0; ii < 5; ++ii) {
#pragma unroll
            for (int r = 0; r < 4; ++r) {
                const int m = wm + ii * 16 + lq * 4 + r;
                if (m < mloc) {
                    const int pp = list[m];
                    float v = acc[ii][jn][r] + bias;
                    v = 0.5f * v * (1.0f + erff(v * 0.70710678118654752f));
                    hh[(size_t)pp * FDIM + n] = f2bf1(v);
                }
            }
        }
    }
}

__global__ __launch_bounds__(256, 2) void gemm2_fb(
    const unsigned short* __restrict__ hh, const float* __restrict__ w2,
    const float* __restrict__ b2, const int* __restrict__ cnt,
    const int* __restrict__ lists, const int* __restrict__ job_e,
    const int* __restrict__ job_mt, const int* __restrict__ njobs,
    const float* __restrict__ wt, float* __restrict__ out0, float* __restrict__ out1)
{
    const int id = blockIdx.x;
    const int j  = (id >> 6) * 8 + (id & 7);
    const int nt = (id >> 3) & 7;
    if (j >= njobs[0]) return;
    const int e = job_e[j], mt = job_mt[j];
    const int count = cnt[e];
    const int* list = lists + e * MAXT + mt * BM;
    const int mloc = min(BM, count - mt * BM);

    __shared__ __align__(16) unsigned short As[2][BM * 64];
    __shared__ __align__(16) unsigned short Bs[2][128 * 64];

    const int t = threadIdx.x, lane = t & 63, wave = t >> 6;
    const int lrow = lane & 15, lq = lane >> 4;
    const int wm = (wave & 1) * 80, wn = (wave >> 1) * 64;

    const int achk = (lane & 7) ^ (lane >> 3);
    const unsigned short* aGp[5];
#pragma unroll
    for (int q = 0; q < 5; ++q) {
        const int r = wave * 40 + q * 8 + (lane >> 3);
        aGp[q] = hh + (size_t)list[min(r, mloc - 1)] * FDIM + achk * 8;
    }
    const int n4 = (t & 31) * 4, kg = t >> 5;
    const float* bG = w2 + (size_t)e * FDIM * DDIM + nt * 128 + n4;

    floatx4 acc[5][4];
#pragma unroll
    for (int ii = 0; ii < 5; ++ii)
#pragma unroll
        for (int jn = 0; jn < 4; ++jn) acc[ii][jn] = (floatx4)0.f;

    floatx4 brvA[8], brvB[8];
    STAGEA(0, 0);
    SBAR();
    LOADB(brvB, 0, DDIM);
    WRITEB(brvB, 0);
    SBAR();
    LOADB(brvA, 64, DDIM);
    asm volatile("s_waitcnt vmcnt(8) lgkmcnt(0)" ::: "memory");
    __builtin_amdgcn_s_barrier();
#pragma unroll 1
    for (int it = 0; it < 15; ++it) {
        const int i = it * 2;
        STEADY(i, 0, brvA, brvB, DDIM);
        STEADY(i + 1, 1, brvB, brvA, DDIM);
    }
    STAGEA(1, 31 * 64);
    WRITEB(brvA, 1);
    SBAR();
    COMPUTE_F(0);
    asm volatile("s_waitcnt vmcnt(0) lgkmcnt(0)" ::: "memory");
    __builtin_amdgcn_s_barrier();
    COMPUTE_F(1);

#pragma unroll
    for (int jn = 0; jn < 4; ++jn) {
        const int n = nt * 128 + wn + jn * 16 + lrow;
        const float bias = b2[e * DDIM + n];
#pragma unroll
        for (int ii = 0; ii < 5; ++ii) {
#pragma unroll
            for (int r = 0; r < 4; ++r) {
                const int m = wm + ii * 16 + lq * 4 + r;
                if (m < mloc) {
                    const int pp = list[m];
                    const int tok = pp >> 1;
                    const float v = (acc[ii][jn][r] + bias) * wt[pp];
                    float* dst = (pp & 1) ? out1 : out0;
                    dst[(size_t)tok * DDIM + n] = v;
                }
            }
        }
    }
}

// ---------------- finalize: out = clip(x + out0 + out1) ----------------
__global__ __launch_bounds__(256) void finalize_kernel(
    const float* __restrict__ x, const float* __restrict__ o1,
    float* __restrict__ out)   // out currently holds out0
{
    const size_t i = ((size_t)blockIdx.x * 256 + threadIdx.x) * 4;
    float4 xv = *(const float4*)(x + i);
    float4 a  = *(const float4*)(out + i);
    float4 b  = *(const float4*)(o1 + i);
    float4 r;
    r.x = fminf(fmaxf(xv.x + a.x + b.x, -100.f), 100.f);
    r.y = fminf(fmaxf(xv.y + a.y + b.y, -100.f), 100.f);
    r.z = fminf(fmaxf(xv.z + a.z + b.z, -100.f), 100.f);
    r.w = fminf(fmaxf(xv.w + a.w + b.w, -100.f), 100.f);
    *(float4*)(out + i) = r;
}

extern "C" void kernel_launch(void* const* d_in, const int* in_sizes, int n_in,
                              void* d_out, int out_size, void* d_ws, size_t ws_size,
                              hipStream_t stream) {
    const float* h  = (const float*)d_in[0];
    const float* gw = (const float*)d_in[1];
    const float* w1 = (const float*)d_in[2];
    const float* b1 = (const float*)d_in[3];
    const float* w2 = (const float*)d_in[4];
    const float* b2 = (const float*)d_in[5];
    float* out = (float*)d_out;

    // workspace layout (bytes)
    char* ws = (char*)d_ws;
    int*   cnt    = (int*)ws;                         // 256
    int*   lists  = (int*)(ws + 256);                 // 114688
    float* wt     = (float*)(ws + 114944);            // 16384 -> 131328
    int*   job_e  = (int*)(ws + 131328);              // 512
    int*   job_mt = (int*)(ws + 131840);              // 512
    int*   njobs  = (int*)(ws + 132352);              // 256 -> 132608
    unsigned short* xb  = (unsigned short*)(ws + 262144);    // 4 MB   -> 4456448
    float* o1           = (float*)(ws + 4456448);            // 8 MB   -> 12845056
    unsigned short* hhb = (unsigned short*)(ws + 12845056);  // 16 MB  -> 29622272
    unsigned short* wb1 = (unsigned short*)(ws + 29622272);  // 56 MB  -> 88342528
    unsigned short* wb2 = (unsigned short*)(ws + 88342528);  // 56 MB  -> 147062784

    cvtx_kernel<<<NTOK * DDIM / (256 * 8), 256, 0, stream>>>(h, xb, cnt);
    gate_kernel<<<NTOK / 4, 256, 0, stream>>>(h, gw, cnt, lists, wt);
    jobs_kernel<<<1, 64, 0, stream>>>(cnt, job_e, job_mt, njobs);

    if (ws_size >= 147062784ull) {
        // retile order: w2 first so wb1 is L3-hottest when gemm1 runs
        retile2_kernel<<<NEXP * 256, 256, 0, stream>>>(w2, wb2);
        retile1_kernel<<<NEXP * 128, 256, 0, stream>>>(w1, wb1);
        gemm1_kernel<<<dim3(FDIM / 128, MAXJOBS), 256, 0, stream>>>(xb, wb1, b1, cnt, lists, job_e, job_mt, njobs, hhb);
        gemm2_kernel<<<dim3(DDIM / 128, MAXJOBS), 256, 0, stream>>>(hhb, wb2, b2, cnt, lists, job_e, job_mt, njobs, wt, out, o1);
    } else {
        gemm1_fb<<<5 * 128, 256, 0, stream>>>(xb, w1, b1, cnt, lists, job_e, job_mt, njobs, hhb);
        gemm2_fb<<<5 * 64, 256, 0, stream>>>(hhb, w2, b2, cnt, lists, job_e, job_mt, njobs, wt, out, o1);
    }
    finalize_kernel<<<NTOK * DDIM / (256 * 4), 256, 0, stream>>>(h, o1, out);
}